// Round 1
// baseline (971.391 us; speedup 1.0000x reference)
//
#include <hip/hip_runtime.h>
#include <math.h>

// BWNet scan: persistent cooperative kernel with custom device-scope barriers.
// Blocks 0..31  : the 64-step sequential scan (3 barriers/step).
// Blocks 32..255: zero unit_logits rows [steps..8192) with nontemporal stores,
//                 overlapping the scan (268 MB output write floor ~43us).

typedef float v4f __attribute__((ext_vector_type(4)));

#define N_ENT 8192
#define EMB   256
#define KD    32
#define ARD   1024
#define UT    233
#define NSCAN 32
#define NZERO 224
#define NBLK  256

// float-index offsets into d_ws (total ~1.13 MB needed)
#define WS_KEYS 0         // 32*8192 floats, k-major: keys[k*8192+j]
#define WS_C0   262144    // 256: b_a0 + relu(W_fe@um + b_fe)
#define WS_RI0  262400    // 256: relu(i0)
#define WS_AR   262656    // 1024: ar state (block b owns slice [32b,32b+32))
#define WS_MASK 263680    // 8192
#define WS_SEL  271872    // 8192
#define WS_PSUM 280064    // 32 per-block sum(v)
#define WS_PMAX 280096    // 32 per-block max(v)
// int-index offsets
#define WS_PIDX 280128    // 32 per-block argmax idx
#define WS_DONE 280160    // 1
#define WS_CTR  280192    // 256 barrier counters (own cache line)

struct Params {
  const float *um, *emask, *enc, *arin, *W_fe, *b_fe, *W_k, *b_k,
              *W_a0, *b_a0, *W_a1, *b_a1, *W_f, *b_f, *W_i0, *b_i0,
              *W_i1, *b_i1, *W_o, *b_o, *ln_g, *ln_b, *W_a3, *b_a3;
  const int* ct;
  float* out;
  float* wsf;
  int*   wsi;
};

// Agent-scope (sc1) store: write-through to the device coherence point so
// readers on other XCDs see it after the barrier without L2 writebacks.
__device__ __forceinline__ void st_af(float* p, float v) {
  __hip_atomic_store(p, v, __ATOMIC_RELAXED, __HIP_MEMORY_SCOPE_AGENT);
}
__device__ __forceinline__ void st_ai(int* p, int v) {
  __hip_atomic_store(p, v, __ATOMIC_RELAXED, __HIP_MEMORY_SCOPE_AGENT);
}

// Grid barrier over the NSCAN scan blocks. __syncthreads drains each wave's
// vmcnt (so all this block's agent stores are at the coherence point) before
// thread 0 arrives. Exit does one ACQUIRE load (buffer_inv) so subsequent
// plain loads refetch fresh data.
__device__ __forceinline__ void gbar(int* ctr, int idx) {
  __syncthreads();
  if (threadIdx.x == 0) {
    __hip_atomic_fetch_add(&ctr[idx], 1, __ATOMIC_RELAXED, __HIP_MEMORY_SCOPE_AGENT);
    int guard = 0;
    while (__hip_atomic_load(&ctr[idx], __ATOMIC_RELAXED, __HIP_MEMORY_SCOPE_AGENT) < NSCAN) {
      __builtin_amdgcn_s_sleep(1);
      if (++guard > (1 << 20)) break;  // failsafe: never hang the GPU
    }
    (void)__hip_atomic_load(&ctr[idx], __ATOMIC_ACQUIRE, __HIP_MEMORY_SCOPE_AGENT);
  }
  __syncthreads();
}

// ---------------- init: keys GEMM, func_embed, state + counters ----------------
__global__ __launch_bounds__(256) void k_init(Params p) {
  __shared__ float enc_s[32 * 260];  // 32 rows x 256, pad 260 vs bank conflicts
  __shared__ float um_s[UT];
  const int tid = threadIdx.x, bid = blockIdx.x;
  float* keys = p.wsf + WS_KEYS;

  if (bid == 0 && tid < UT) um_s[tid] = p.um[tid];
  if (bid == 1) for (int i = tid; i < ARD; i += 256) p.wsf[WS_AR + i] = p.arin[i];
  if (bid == 2) for (int i = tid; i < N_ENT; i += 256) { p.wsf[WS_MASK + i] = p.emask[i]; p.wsf[WS_SEL + i] = 0.f; }
  if (bid == 3) { p.wsi[WS_CTR + tid] = 0; if (tid == 0) p.wsi[WS_DONE] = 0; }

  // stage 32 entity rows (this block's columns j0..j0+31)
  const int j0 = bid * 32;
  #pragma unroll
  for (int i = 0; i < 8; ++i) {
    int idx = i * 256 + tid;           // float4 units, 0..2047
    int row = idx >> 6, c4 = idx & 63;
    v4f v = *(const v4f*)(p.enc + (size_t)(j0 + row) * EMB + c4 * 4);
    *(v4f*)&enc_s[row * 260 + c4 * 4] = v;
  }
  __syncthreads();
  {
    const int jl = tid >> 3, kg = tid & 7;  // 32 j x 8 k-groups
    float acc[4];
    #pragma unroll
    for (int kk = 0; kk < 4; ++kk) acc[kk] = p.b_k[kg * 4 + kk];
    for (int e4 = 0; e4 < 64; ++e4) {
      v4f x = *(const v4f*)&enc_s[jl * 260 + e4 * 4];
      #pragma unroll
      for (int kk = 0; kk < 4; ++kk) {
        v4f w = *(const v4f*)(p.W_k + (size_t)(kg * 4 + kk) * EMB + e4 * 4);
        acc[kk] += x.x * w.x + x.y * w.y + x.z * w.z + x.w * w.w;
      }
    }
    const int j = j0 + jl;
    #pragma unroll
    for (int kk = 0; kk < 4; ++kk) keys[(size_t)(kg * 4 + kk) * N_ENT + j] = acc[kk];
  }
  if (bid == 0) {  // c0 = b_a0 + relu(W_fe @ um + b_fe)
    float a = p.b_fe[tid];
    const float* wr = p.W_fe + (size_t)tid * UT;
    for (int u = 0; u < UT; ++u) a += wr[u] * um_s[u];
    p.wsf[WS_C0 + tid] = fmaxf(a, 0.f) + p.b_a0[tid];
  }
}

// ---------------- main: scan (blocks 0..31) + output zeroing (32..255) ----------------
__global__ __launch_bounds__(256, 1) void k_scan(Params p) {
  const int tid = threadIdx.x, bid = blockIdx.x;
  int ctv = p.ct[0];
  const int steps = ctv < 0 ? 0 : (ctv > 64 ? 64 : ctv);
  const size_t NN = (size_t)N_ENT * N_ENT;

  if (bid >= NSCAN) {  // -------- zero role --------
    v4f z = (v4f){0.f, 0.f, 0.f, 0.f};
    v4f* o4 = (v4f*)p.out;
    const size_t tot = NN / 4;
    for (size_t i = (size_t)steps * (N_ENT / 4) + (size_t)(bid - NSCAN) * 256 + tid;
         i < tot; i += (size_t)NZERO * 256)
      __builtin_nontemporal_store(z, o4 + i);
    return;
  }

  // -------- scan role --------
  __shared__ float kslice[KD * 256];     // this block's 256 key columns
  __shared__ float wa3s[32 * 33];        // W_a3 rows [32b,32b+32), pad 33
  __shared__ float ri0_s[8 * 33];        // relu(i0), 256 padded per 32
  __shared__ float x_i1[32], q_s[32], h_s[32], qnf[32];
  __shared__ float garr[4 * 32], fog[32], rem[32], og[32], cent[32];
  __shared__ float b_a1s[32], gb_s[4 * 32], b_a3s[32], lng_s[32], lnb_s[32], c0own[8];
  __shared__ float reds[4], rmaxs[4];
  __shared__ int ridxs[4];
  __shared__ float ssum_s, maskv_s;
  __shared__ int pick_s, active_s, nanfree_s;
  __shared__ int ph_pick, ph_hit, ph_nf;

  float* keys = p.wsf + WS_KEYS;
  float* ri0w = p.wsf + WS_RI0;
  float* arw  = p.wsf + WS_AR;
  float* maskw = p.wsf + WS_MASK;
  float* selw  = p.wsf + WS_SEL;
  float* psum = p.wsf + WS_PSUM;
  float* pmax = p.wsf + WS_PMAX;
  int* pidx  = p.wsi + WS_PIDX;
  int* donep = p.wsi + WS_DONE;
  int* ctrp  = p.wsi + WS_CTR;

  // ---- preamble: weights into LDS / registers ----
  for (int idx = tid; idx < KD * 256; idx += 256)
    kslice[idx] = keys[(size_t)(idx >> 8) * N_ENT + (bid << 8) + (idx & 255)];
  {
    const int r = tid >> 3, c4 = tid & 7;
    v4f v = *(const v4f*)(p.W_a3 + (size_t)(bid * 32 + r) * KD + c4 * 4);
    float* d = &wa3s[r * 33 + c4 * 4];
    d[0] = v.x; d[1] = v.y; d[2] = v.z; d[3] = v.w;
  }
  if (tid < 32) {
    b_a1s[tid] = p.b_a1[tid];
    b_a3s[tid] = p.b_a3[bid * 32 + tid];
    lng_s[tid] = p.ln_g[tid]; lnb_s[tid] = p.ln_b[tid];
    q_s[tid] = 0.f; h_s[tid] = 0.f; qnf[tid] = 0.f; x_i1[tid] = 0.f;
  }
  if (tid < 128) {
    const int g = tid >> 5, r = tid & 31;
    const float* bg = (g == 0) ? p.b_f : (g == 1) ? p.b_i0 : (g == 2) ? p.b_i1 : p.b_o;
    gb_s[tid] = bg[r];
  }
  if (tid < 8) c0own[tid] = p.wsf[WS_C0 + bid * 8 + tid];
  if (tid == 0) { active_s = 1; ph_hit = 0; ph_pick = 0; ph_nf = 1; }

  v4f w0[8];  // W_a0 rows [8b,8b+8): thread = (row tid>>5, cols (tid&31)*32..+32)
  { const float* s = p.W_a0 + (size_t)(bid * 8 + (tid >> 5)) * ARD + (tid & 31) * 32;
    #pragma unroll
    for (int i = 0; i < 8; ++i) w0[i] = ((const v4f*)s)[i]; }
  v4f w1[8];  // W_a1: thread = (row tid>>3, cols (tid&7)*32..+32)
  { const float* s = p.W_a1 + (size_t)(tid >> 3) * EMB + (tid & 7) * 32;
    #pragma unroll
    for (int i = 0; i < 8; ++i) w1[i] = ((const v4f*)s)[i]; }
  v4f wg[8];  // LSTM gates: 128 rows x 2 halves
  { const int rowg = tid >> 1, g = rowg >> 5, r = rowg & 31, half = tid & 1;
    const float* W = (g == 0) ? p.W_f : (g == 1) ? p.W_i0 : (g == 2) ? p.W_i1 : p.W_o;
    const float* s = W + r * 64 + half * 32;
    #pragma unroll
    for (int i = 0; i < 8; ++i) wg[i] = ((const v4f*)s)[i]; }
  __syncthreads();

  float v_reg = 0.f;
  for (int t = 0; t < steps; ++t) {
    // ==== Phase I: mask/sel/done updates for step t-1; i0 = W_a0@ar + c0 ====
    if (bid == 0 && tid == 0 && ph_hit) {
      st_af(&maskw[ph_pick], 0.f);
      st_af(&selw[ph_pick], 1.f);
      if (!ph_nf) st_ai(donep, 1);
    }
    {
      const int seg = tid & 31, rl = tid >> 5;
      const float* a = arw + seg * 32;
      float pa = 0.f;
      #pragma unroll
      for (int i = 0; i < 8; ++i) {
        v4f av = *(const v4f*)(a + 4 * i);
        pa += w0[i].x * av.x + w0[i].y * av.y + w0[i].z * av.z + w0[i].w * av.w;
      }
      #pragma unroll
      for (int m = 16; m; m >>= 1) pa += __shfl_xor(pa, m);
      if (seg == 0) st_af(&ri0w[bid * 8 + rl], fmaxf(pa + c0own[rl], 0.f));
    }
    gbar(ctrp, 3 * t);

    // ==== Phase L (redundant per block): i1, LSTM, layernorms -> qn ====
    if (tid < 64) {
      v4f v4 = *(const v4f*)(ri0w + tid * 4);
      const int j = tid * 4;
      float* d = &ri0_s[(j >> 5) * 33 + (j & 31)];
      d[0] = v4.x; d[1] = v4.y; d[2] = v4.z; d[3] = v4.w;
    }
    if (tid == 0)
      active_s = (__hip_atomic_load(donep, __ATOMIC_RELAXED, __HIP_MEMORY_SCOPE_AGENT) == 0) ? 1 : 0;
    __syncthreads();
    {
      const int r = tid >> 3, s8 = tid & 7;
      float p1 = 0.f;
      #pragma unroll
      for (int i = 0; i < 8; ++i) {
        const float* xx = &ri0_s[s8 * 33 + 4 * i];
        p1 += w1[i].x * xx[0] + w1[i].y * xx[1] + w1[i].z * xx[2] + w1[i].w * xx[3];
      }
      #pragma unroll
      for (int m = 4; m; m >>= 1) p1 += __shfl_xor(p1, m);
      if (s8 == 0) x_i1[r] = fmaxf(p1 + b_a1s[r], 0.f);
    }
    __syncthreads();
    {
      const int rowg = tid >> 1, g = rowg >> 5, half = tid & 1;
      const float* xsrc = half ? q_s : x_i1;  // x = concat(i1, q)
      float pg = 0.f;
      #pragma unroll
      for (int i = 0; i < 8; ++i)
        pg += wg[i].x * xsrc[4 * i] + wg[i].y * xsrc[4 * i + 1] +
              wg[i].z * xsrc[4 * i + 2] + wg[i].w * xsrc[4 * i + 3];
      pg += __shfl_xor(pg, 1);
      if (!half) {
        pg += gb_s[rowg];
        garr[rowg] = (g == 2) ? tanhf(pg) : 1.f / (1.f + __expf(-pg));
      }
    }
    __syncthreads();
    {
      const int w = tid >> 6, k = tid & 63;
      if (w < 3 && k < 32) {  // 3 layernorms in parallel (one per wave)
        float a = (w == 0) ? garr[k] : (w == 1) ? garr[32 + k] * garr[64 + k] : garr[96 + k];
        float s = a;
        #pragma unroll
        for (int m = 16; m; m >>= 1) s += __shfl_xor(s, m);
        const float mean = s * (1.f / 32.f);
        const float d = a - mean;
        float vv = d * d;
        #pragma unroll
        for (int m = 16; m; m >>= 1) vv += __shfl_xor(vv, m);
        vv *= (1.f / 32.f);
        const float y = d * rsqrtf(vv + 1e-5f) * lng_s[k] + lnb_s[k];
        if (w == 0) fog[k] = y; else if (w == 1) rem[k] = y; else og[k] = y;
      }
    }
    __syncthreads();
    if (tid < 32) {
      const float nh = rem[tid] + fog[tid] * h_s[tid];
      const float qv = tanhf(nh) * og[tid];
      qnf[tid] = qv;                       // sweep always uses fresh qn
      if (active_s) { h_s[tid] = nh; q_s[tid] = qv; }  // state gated by active
    }
    __syncthreads();

    // ==== Phase S: sigmoid sweep over this block's 256 key columns ====
    {
      float dot = 0.f;
      #pragma unroll
      for (int k = 0; k < 32; ++k) dot += qnf[k] * kslice[k * 256 + tid];
      const float sig = 1.f / (1.f + __expf(-dot));
      const float v = __expf(__logf(sig) / 0.8f);  // sig^(1/TEMP)
      v_reg = v;
      float sv = v, mv = v;
      int mi = (bid << 8) + tid;
      #pragma unroll
      for (int m = 32; m; m >>= 1) {
        sv += __shfl_xor(sv, m);
        const float ov = __shfl_xor(mv, m);
        const int oi = __shfl_xor(mi, m);
        if (ov > mv || (ov == mv && oi < mi)) { mv = ov; mi = oi; }
      }
      const int wv = tid >> 6;
      if ((tid & 63) == 0) { reds[wv] = sv; rmaxs[wv] = mv; ridxs[wv] = mi; }
      __syncthreads();
      if (tid == 0) {
        float S = ((reds[0] + reds[1]) + reds[2]) + reds[3];
        float M = rmaxs[0]; int I = ridxs[0];
        #pragma unroll
        for (int i2 = 1; i2 < 4; ++i2)
          if (rmaxs[i2] > M || (rmaxs[i2] == M && ridxs[i2] < I)) { M = rmaxs[i2]; I = ridxs[i2]; }
        st_af(&psum[bid], S); st_af(&pmax[bid], M); st_ai(&pidx[bid], I);
      }
    }
    gbar(ctrp, 3 * t + 1);

    // ==== Phase R (redundant): global reduce, row write, delta, ar update ====
    if (tid < 32) {
      float s = psum[tid], m = pmax[tid];
      int ii = pidx[tid];
      #pragma unroll
      for (int mm = 16; mm; mm >>= 1) {
        s += __shfl_xor(s, mm);
        const float om = __shfl_xor(m, mm);
        const int oi = __shfl_xor(ii, mm);
        if (om > m || (om == m && oi < ii)) { m = om; ii = oi; }
      }
      const float kv = keys[(size_t)tid * N_ENT + ii];  // keys[:, pick]
      float mn = kv;
      #pragma unroll
      for (int mm = 16; mm; mm >>= 1) mn += __shfl_xor(mn, mm);
      mn *= (1.f / 32.f);
      const float cv = kv - mn;
      cent[tid] = cv;
      const unsigned long long bb = __ballot(cv != cv);
      if (tid == 0) {
        ssum_s = s; pick_s = ii;
        maskv_s = maskw[ii];
        nanfree_s = (bb == 0) ? 1 : 0;
      }
    }
    __syncthreads();
    {
      const float ssum = ssum_s;
      const int valid = (ssum != 0.f);
      const int act = active_s;
      const int hit = (act && valid && (maskv_s != 0.f)) ? 1 : 0;
      const float rowv = (act && valid) ? (v_reg / ssum) : 0.f;
      __builtin_nontemporal_store(rowv, p.out + (size_t)t * N_ENT + (bid << 8) + tid);
      if (tid < 32) {
        float dl = b_a3s[tid];
        #pragma unroll
        for (int c = 0; c < 32; ++c) dl += wa3s[tid * 33 + c] * cent[c];
        if (hit && nanfree_s) {
          const float cur = arw[bid * 32 + tid];
          st_af(&arw[bid * 32 + tid], cur + fmaxf(dl, 0.f));
        }
      }
      if (tid == 0) { ph_pick = pick_s; ph_hit = hit; ph_nf = nanfree_s; }
    }
    gbar(ctrp, 3 * t + 2);
  }

  // ==== epilogue: sel_out and ar_out ====
  if (bid == 0) {
    if (tid == 0 && ph_hit) st_af(&selw[ph_pick], 1.f);
    __syncthreads();
    for (int i = tid; i < N_ENT; i += 256) p.out[NN + i] = selw[i];
  } else if (bid == 1) {
    for (int i = tid; i < ARD; i += 256) p.out[NN + N_ENT + i] = arw[i];
  }
}

extern "C" void kernel_launch(void* const* d_in, const int* in_sizes, int n_in,
                              void* d_out, int out_size, void* d_ws, size_t ws_size,
                              hipStream_t stream) {
  (void)in_sizes; (void)n_in; (void)out_size; (void)ws_size;
  Params p;
  p.um    = (const float*)d_in[0];
  p.emask = (const float*)d_in[1];
  p.enc   = (const float*)d_in[2];
  p.arin  = (const float*)d_in[3];
  p.W_fe  = (const float*)d_in[4];
  p.b_fe  = (const float*)d_in[5];
  p.W_k   = (const float*)d_in[6];
  p.b_k   = (const float*)d_in[7];
  p.W_a0  = (const float*)d_in[8];
  p.b_a0  = (const float*)d_in[9];
  p.W_a1  = (const float*)d_in[10];
  p.b_a1  = (const float*)d_in[11];
  p.W_f   = (const float*)d_in[12];
  p.b_f   = (const float*)d_in[13];
  p.W_i0  = (const float*)d_in[14];
  p.b_i0  = (const float*)d_in[15];
  p.W_i1  = (const float*)d_in[16];
  p.b_i1  = (const float*)d_in[17];
  p.W_o   = (const float*)d_in[18];
  p.b_o   = (const float*)d_in[19];
  p.ln_g  = (const float*)d_in[20];
  p.ln_b  = (const float*)d_in[21];
  p.W_a3  = (const float*)d_in[22];
  p.b_a3  = (const float*)d_in[23];
  p.ct    = (const int*)d_in[24];
  p.out   = (float*)d_out;
  p.wsf   = (float*)d_ws;
  p.wsi   = (int*)d_ws;

  hipLaunchKernelGGL(k_init, dim3(NBLK), dim3(256), 0, stream, p);
  hipLaunchKernelGGL(k_scan, dim3(NBLK), dim3(256), 0, stream, p);
}